// Round 1
// baseline (852.801 us; speedup 1.0000x reference)
//
#include <hip/hip_runtime.h>
#include <hip/hip_bf16.h>

// Problem: B=8, T=2048, D_IN=D_EMB=D_OUT=1024
#define B_DIM 8
#define T_DIM 2048
#define E_DIM 1024

typedef __attribute__((ext_vector_type(8))) short short8;
typedef __attribute__((ext_vector_type(4))) float f32x4;

__device__ __forceinline__ unsigned short f2bf(float f) {
  union { float f; unsigned u; } v; v.f = f;
  unsigned r = v.u + 0x7fffu + ((v.u >> 16) & 1u);
  return (unsigned short)(r >> 16);
}

__device__ __forceinline__ void async16(const void* g, void* l) {
  __builtin_amdgcn_global_load_lds(
      (const __attribute__((address_space(1))) unsigned int*)g,
      (__attribute__((address_space(3))) unsigned int*)l, 16, 0, 0);
}

__device__ __forceinline__ void storeC(float* p, float v) { *p = v; }
__device__ __forceinline__ void storeC(unsigned short* p, float v) { *p = f2bf(v); }

// ---------------- fp32 -> bf16 conversion (vectorized) ----------------
__global__ __launch_bounds__(256) void cvt_bf16(const float4* __restrict__ in,
                                                ushort4* __restrict__ out) {
  size_t i = (size_t)blockIdx.x * 256 + threadIdx.x;
  float4 v = in[i];
  ushort4 o;
  o.x = f2bf(v.x); o.y = f2bf(v.y); o.z = f2bf(v.z); o.w = f2bf(v.w);
  out[i] = o;
}

// ---------------- m97-style bf16 GEMM: C[M,N] = A[M,K] * B[N,K]^T ----------------
// EPI 0: none; 1: +biasv[n]; 2: *scale + biasm[m*ldbm+n]
#define BM 128
#define BN 128
#define BK 32

template <int EPI, typename OutT>
__global__ __launch_bounds__(256) void gemm_bt(
    const unsigned short* __restrict__ A, int lda,
    const unsigned short* __restrict__ Bmat, int ldb,
    OutT* __restrict__ C, int ldc, int K,
    const float* __restrict__ biasv,
    const float* __restrict__ biasm, int ldbm, float scale) {
  __shared__ __align__(16) unsigned short Al[BM * BK];
  __shared__ __align__(16) unsigned short Bl[BN * BK];
  const int tid = threadIdx.x;
  const int wid = tid >> 6, lane = tid & 63;
  const int wm = wid >> 1, wn = wid & 1;
  const int tm = blockIdx.x * BM, tn = blockIdx.y * BN;
  const int l16 = lane & 15, lk = lane >> 4;

  f32x4 acc[4][4];
#pragma unroll
  for (int i = 0; i < 4; ++i)
#pragma unroll
    for (int j = 0; j < 4; ++j) acc[i][j] = (f32x4){0.f, 0.f, 0.f, 0.f};

  for (int k0 = 0; k0 < K; k0 += BK) {
    __syncthreads();
    // stage A tile [BM][BK] (8192B): 512 x 16B chunks, 256 threads, 2 rounds
#pragma unroll
    for (int it = 0; it < 2; ++it) {
      int chunk = it * 256 + tid;
      int row = chunk >> 2;
      int cb = (chunk & 3) * 16;
      const char* g = (const char*)(A + (size_t)(tm + row) * lda + k0) + cb;
      async16(g, ((char*)Al) + it * 4096 + wid * 1024);
    }
#pragma unroll
    for (int it = 0; it < 2; ++it) {
      int chunk = it * 256 + tid;
      int row = chunk >> 2;
      int cb = (chunk & 3) * 16;
      const char* g = (const char*)(Bmat + (size_t)(tn + row) * ldb + k0) + cb;
      async16(g, ((char*)Bl) + it * 4096 + wid * 1024);
    }
    __syncthreads();

    short8 a[4], b[4];
#pragma unroll
    for (int i = 0; i < 4; ++i)
      a[i] = *(const short8*)&Al[(wm * 64 + i * 16 + l16) * BK + lk * 8];
#pragma unroll
    for (int j = 0; j < 4; ++j)
      b[j] = *(const short8*)&Bl[(wn * 64 + j * 16 + l16) * BK + lk * 8];
#pragma unroll
    for (int i = 0; i < 4; ++i)
#pragma unroll
      for (int j = 0; j < 4; ++j)
        acc[i][j] = __builtin_amdgcn_mfma_f32_16x16x32_bf16(a[i], b[j], acc[i][j], 0, 0, 0);
  }

  // epilogue: D row=(lane>>4)*4+r, col=lane&15 (verified gfx950 mapping)
#pragma unroll
  for (int i = 0; i < 4; ++i)
#pragma unroll
    for (int j = 0; j < 4; ++j) {
      int col = tn + wn * 64 + j * 16 + l16;
      int rbase = tm + wm * 64 + i * 16 + lk * 4;
#pragma unroll
      for (int r = 0; r < 4; ++r) {
        float v = acc[i][j][r];
        int row = rbase + r;
        if (EPI == 1) v += biasv[col];
        if (EPI == 2) v = v * scale + biasm[(size_t)row * ldbm + col];
        storeC(&C[(size_t)row * ldc + col], v);
      }
    }
}

// ---------------- V transpose: VT[b][d][s] = V[b][s][d] (from QKV buffer) ----------------
__global__ __launch_bounds__(256) void transpose_v(const unsigned short* __restrict__ qkv,
                                                   unsigned short* __restrict__ vt) {
  __shared__ unsigned short tl[64][65];
  const int b = blockIdx.z;
  const int s0 = blockIdx.x * 64, d0 = blockIdx.y * 64;
  const int tx = threadIdx.x & 63, ty = threadIdx.x >> 6;
#pragma unroll
  for (int it = 0; it < 16; ++it) {
    int r = it * 4 + ty;
    tl[r][tx] = qkv[((size_t)b * T_DIM + s0 + r) * 3072 + 2048 + d0 + tx];
  }
  __syncthreads();
#pragma unroll
  for (int it = 0; it < 16; ++it) {
    int r = it * 4 + ty;
    vt[((size_t)b * E_DIM + d0 + r) * T_DIM + s0 + tx] = tl[tx][r];
  }
}

// ---------------- row softmax: P(bf16) = softmax(S row), row length 2048 ----------------
__global__ __launch_bounds__(256) void softmax_rows(const float* __restrict__ S,
                                                    unsigned short* __restrict__ P) {
  const int t = blockIdx.x;
  const float* row = S + (size_t)t * T_DIM;
  const int tid = threadIdx.x;
  const int wid = tid >> 6;
  __shared__ float red[8];

  float4 v0 = ((const float4*)row)[tid * 2];
  float4 v1 = ((const float4*)row)[tid * 2 + 1];
  float m = fmaxf(fmaxf(fmaxf(v0.x, v0.y), fmaxf(v0.z, v0.w)),
                  fmaxf(fmaxf(v1.x, v1.y), fmaxf(v1.z, v1.w)));
#pragma unroll
  for (int o = 1; o < 64; o <<= 1) m = fmaxf(m, __shfl_xor(m, o));
  if ((tid & 63) == 0) red[wid] = m;
  __syncthreads();
  m = fmaxf(fmaxf(red[0], red[1]), fmaxf(red[2], red[3]));

  float e0 = __expf(v0.x - m), e1 = __expf(v0.y - m), e2 = __expf(v0.z - m), e3 = __expf(v0.w - m);
  float e4 = __expf(v1.x - m), e5 = __expf(v1.y - m), e6 = __expf(v1.z - m), e7 = __expf(v1.w - m);
  float s = ((e0 + e1) + (e2 + e3)) + ((e4 + e5) + (e6 + e7));
#pragma unroll
  for (int o = 1; o < 64; o <<= 1) s += __shfl_xor(s, o);
  if ((tid & 63) == 0) red[4 + wid] = s;
  __syncthreads();
  s = (red[4] + red[5]) + (red[6] + red[7]);
  float inv = 1.0f / s;

  ushort4 p0, p1;
  p0.x = f2bf(e0 * inv); p0.y = f2bf(e1 * inv); p0.z = f2bf(e2 * inv); p0.w = f2bf(e3 * inv);
  p1.x = f2bf(e4 * inv); p1.y = f2bf(e5 * inv); p1.z = f2bf(e6 * inv); p1.w = f2bf(e7 * inv);
  ushort4* prow = (ushort4*)(P + (size_t)t * T_DIM);
  prow[tid * 2] = p0;
  prow[tid * 2 + 1] = p1;
}

// ---------------- launch ----------------
extern "C" void kernel_launch(void* const* d_in, const int* in_sizes, int n_in,
                              void* d_out, int out_size, void* d_ws, size_t ws_size,
                              hipStream_t stream) {
  const float* x = (const float*)d_in[0];     // [8,2048,1024]
  const float* bias = (const float*)d_in[1];  // [2048,2048]
  const float* Wqkv = (const float*)d_in[2];  // [3072,1024]
  const float* bqkv = (const float*)d_in[3];  // [3072]
  const float* Wout = (const float*)d_in[4];  // [1024,1024]
  const float* bout = (const float*)d_in[5];  // [1024]
  float* out = (float*)d_out;                 // [8,2048,1024] fp32

  char* ws = (char*)d_ws;
  unsigned short* Xb    = (unsigned short*)(ws + 0);          // 33.5MB
  unsigned short* Wqkvb = (unsigned short*)(ws + 33554432);   // 6.3MB
  unsigned short* Woutb = (unsigned short*)(ws + 39845888);   // 2.1MB
  unsigned short* QKVb  = (unsigned short*)(ws + 41943040);   // 100.7MB [b,t,3072]
  unsigned short* VTb   = (unsigned short*)(ws + 142606336);  // 33.5MB  [b,1024,2048]
  unsigned short* Valb  = (unsigned short*)(ws + 176160768);  // 33.5MB  [b,t,1024]
  float*          S     = (float*)(ws + 209715200);           // 16.8MB  [2048,2048] (per-batch reuse)
  unsigned short* P     = (unsigned short*)(ws + 226492416);  // 8.4MB   [2048,2048]

  // 1) fp32 -> bf16 conversions
  cvt_bf16<<<16384, 256, 0, stream>>>((const float4*)x, (ushort4*)Xb);         // 16.7M elems
  cvt_bf16<<<3072, 256, 0, stream>>>((const float4*)Wqkv, (ushort4*)Wqkvb);    // 3.1M
  cvt_bf16<<<1024, 256, 0, stream>>>((const float4*)Wout, (ushort4*)Woutb);    // 1.0M

  // 2) QKV projection: [16384,3072] = Xb[16384,1024] * Wqkv[3072,1024]^T + bqkv
  gemm_bt<1, unsigned short><<<dim3(128, 24), 256, 0, stream>>>(
      Xb, 1024, Wqkvb, 1024, QKVb, 3072, 1024, bqkv, nullptr, 0, 0.f);

  // 3) V transpose for PV GEMM (B^T layout)
  transpose_v<<<dim3(32, 16, B_DIM), 256, 0, stream>>>(QKVb, VTb);

  // 4) per-batch attention
  for (int b = 0; b < B_DIM; ++b) {
    const unsigned short* Qb = QKVb + (size_t)b * T_DIM * 3072;
    const unsigned short* Kb = Qb + 1024;
    // logits: S[t,s] = (Q_t . K_s) / 32 + bias[t,s]
    gemm_bt<2, float><<<dim3(16, 16), 256, 0, stream>>>(
        Qb, 3072, Kb, 3072, S, T_DIM, 1024, nullptr, bias, T_DIM, 0.03125f);
    softmax_rows<<<T_DIM, 256, 0, stream>>>(S, P);
    // values: [2048,1024] = P[2048,2048] * VT[1024,2048]^T
    gemm_bt<0, unsigned short><<<dim3(16, 8), 256, 0, stream>>>(
        P, T_DIM, VTb + (size_t)b * E_DIM * T_DIM, T_DIM,
        Valb + (size_t)b * T_DIM * E_DIM, E_DIM, T_DIM, nullptr, nullptr, 0, 0.f);
  }

  // 5) output projection: out[16384,1024] = Val[16384,1024] * Wout[1024,1024]^T + bout
  gemm_bt<1, float><<<dim3(128, 8), 256, 0, stream>>>(
      Valb, 1024, Woutb, 1024, out, 1024, 1024, bout, nullptr, 0, 0.f);
}

// Round 2
// 590.946 us; speedup vs baseline: 1.4431x; 1.4431x over previous
//
#include <hip/hip_runtime.h>
#include <hip/hip_bf16.h>

// Problem: B=8, T=2048, D_IN=D_EMB=D_OUT=1024
#define B_DIM 8
#define T_DIM 2048
#define E_DIM 1024

typedef __attribute__((ext_vector_type(8))) short short8;
typedef __attribute__((ext_vector_type(4))) float f32x4;

__device__ __forceinline__ unsigned short f2bf(float f) {
  union { float f; unsigned u; } v; v.f = f;
  unsigned r = v.u + 0x7fffu + ((v.u >> 16) & 1u);
  return (unsigned short)(r >> 16);
}
__device__ __forceinline__ float bf2f(unsigned short u) {
  union { unsigned u; float f; } v; v.u = ((unsigned)u) << 16;
  return v.f;
}

__device__ __forceinline__ void async16(const void* g, void* l) {
  __builtin_amdgcn_global_load_lds(
      (const __attribute__((address_space(1))) unsigned int*)g,
      (__attribute__((address_space(3))) unsigned int*)l, 16, 0, 0);
}

__device__ __forceinline__ void storeC(float* p, float v) { *p = v; }
__device__ __forceinline__ void storeC(unsigned short* p, float v) { *p = f2bf(v); }

// ---------------- fp32 -> bf16 conversion (vectorized) ----------------
__global__ __launch_bounds__(256) void cvt_bf16(const float4* __restrict__ in,
                                                ushort4* __restrict__ out) {
  size_t i = (size_t)blockIdx.x * 256 + threadIdx.x;
  float4 v = in[i];
  ushort4 o;
  o.x = f2bf(v.x); o.y = f2bf(v.y); o.z = f2bf(v.z); o.w = f2bf(v.w);
  out[i] = o;
}

// ---------------- m97-style bf16 GEMM: C[M,N] = A[M,K] * B[N,K]^T (batched z) --------
// EPI 0: none; 1: +biasv[n]; 2: *scale + bf2f(biasm[m*ldbm+n])
// LDS k-chunk swizzle: LDS chunk (row,q) holds global chunk q^((row>>1)&3).
// Source is pre-swizzled (global_load_lds dest is linear); read XORs the same.
#define BM 128
#define BN 128
#define BK 32

template <int EPI, typename OutT>
__global__ __launch_bounds__(256) void gemm_bt(
    const unsigned short* __restrict__ A, int lda, long long strA,
    const unsigned short* __restrict__ Bmat, int ldb, long long strB,
    OutT* __restrict__ C, int ldc, long long strC, int K,
    const float* __restrict__ biasv,
    const unsigned short* __restrict__ biasm, int ldbm, float scale) {
  __shared__ __align__(16) unsigned short Al[BM * BK];
  __shared__ __align__(16) unsigned short Bl[BN * BK];
  const int tid = threadIdx.x;
  const int wid = tid >> 6, lane = tid & 63;
  const int wm = wid >> 1, wn = wid & 1;
  const int tm = blockIdx.x * BM, tn = blockIdx.y * BN;
  const int l16 = lane & 15, lk = lane >> 4;

  A += (size_t)blockIdx.z * strA;
  Bmat += (size_t)blockIdx.z * strB;
  C += (size_t)blockIdx.z * strC;

  f32x4 acc[4][4];
#pragma unroll
  for (int i = 0; i < 4; ++i)
#pragma unroll
    for (int j = 0; j < 4; ++j) acc[i][j] = (f32x4){0.f, 0.f, 0.f, 0.f};

  // swizzled k-slot for fragment reads: row bits [2:1] come from l16
  const int ks = (lk ^ ((l16 >> 1) & 3)) * 8;

  for (int k0 = 0; k0 < K; k0 += BK) {
    __syncthreads();
    // stage A tile [BM][BK] (8192B): 512 x 16B chunks, source k-chunk pre-swizzled
#pragma unroll
    for (int it = 0; it < 2; ++it) {
      int chunk = it * 256 + tid;
      int row = chunk >> 2;
      int q = chunk & 3;
      int qs = q ^ ((row >> 1) & 3);
      const char* g = (const char*)(A + (size_t)(tm + row) * lda + k0) + qs * 16;
      async16(g, ((char*)Al) + it * 4096 + wid * 1024);
    }
#pragma unroll
    for (int it = 0; it < 2; ++it) {
      int chunk = it * 256 + tid;
      int row = chunk >> 2;
      int q = chunk & 3;
      int qs = q ^ ((row >> 1) & 3);
      const char* g = (const char*)(Bmat + (size_t)(tn + row) * ldb + k0) + qs * 16;
      async16(g, ((char*)Bl) + it * 4096 + wid * 1024);
    }
    __syncthreads();

    short8 a[4], b[4];
#pragma unroll
    for (int i = 0; i < 4; ++i)
      a[i] = *(const short8*)&Al[(wm * 64 + i * 16 + l16) * BK + ks];
#pragma unroll
    for (int j = 0; j < 4; ++j)
      b[j] = *(const short8*)&Bl[(wn * 64 + j * 16 + l16) * BK + ks];
#pragma unroll
    for (int i = 0; i < 4; ++i)
#pragma unroll
      for (int j = 0; j < 4; ++j)
        acc[i][j] = __builtin_amdgcn_mfma_f32_16x16x32_bf16(a[i], b[j], acc[i][j], 0, 0, 0);
  }

  // epilogue: D row=(lane>>4)*4+r, col=lane&15 (verified gfx950 mapping)
#pragma unroll
  for (int i = 0; i < 4; ++i)
#pragma unroll
    for (int j = 0; j < 4; ++j) {
      int col = tn + wn * 64 + j * 16 + l16;
      int rbase = tm + wm * 64 + i * 16 + lk * 4;
#pragma unroll
      for (int r = 0; r < 4; ++r) {
        float v = acc[i][j][r];
        int row = rbase + r;
        if (EPI == 1) v += biasv[col];
        if (EPI == 2) v = v * scale + bf2f(biasm[(size_t)row * ldbm + col]);
        storeC(&C[(size_t)row * ldc + col], v);
      }
    }
}

// ---------------- V transpose: VT[b][d][s] = V[b][s][d] (from QKV buffer) ----------------
__global__ __launch_bounds__(256) void transpose_v(const unsigned short* __restrict__ qkv,
                                                   unsigned short* __restrict__ vt) {
  __shared__ unsigned short tl[64][65];
  const int b = blockIdx.z;
  const int s0 = blockIdx.x * 64, d0 = blockIdx.y * 64;
  const int tx = threadIdx.x & 63, ty = threadIdx.x >> 6;
#pragma unroll
  for (int it = 0; it < 16; ++it) {
    int r = it * 4 + ty;
    tl[r][tx] = qkv[((size_t)b * T_DIM + s0 + r) * 3072 + 2048 + d0 + tx];
  }
  __syncthreads();
#pragma unroll
  for (int it = 0; it < 16; ++it) {
    int r = it * 4 + ty;
    vt[((size_t)b * E_DIM + d0 + r) * T_DIM + s0 + tx] = tl[tx][r];
  }
}

// ---------------- row softmax: P(bf16) = softmax(S row), row length 2048 ----------------
__global__ __launch_bounds__(256) void softmax_rows(const float* __restrict__ S,
                                                    unsigned short* __restrict__ P) {
  const size_t t = (size_t)blockIdx.y * T_DIM + blockIdx.x;
  const float* row = S + t * T_DIM;
  const int tid = threadIdx.x;
  const int wid = tid >> 6;
  __shared__ float red[8];

  float4 v0 = ((const float4*)row)[tid * 2];
  float4 v1 = ((const float4*)row)[tid * 2 + 1];
  float m = fmaxf(fmaxf(fmaxf(v0.x, v0.y), fmaxf(v0.z, v0.w)),
                  fmaxf(fmaxf(v1.x, v1.y), fmaxf(v1.z, v1.w)));
#pragma unroll
  for (int o = 1; o < 64; o <<= 1) m = fmaxf(m, __shfl_xor(m, o));
  if ((tid & 63) == 0) red[wid] = m;
  __syncthreads();
  m = fmaxf(fmaxf(red[0], red[1]), fmaxf(red[2], red[3]));

  float e0 = __expf(v0.x - m), e1 = __expf(v0.y - m), e2 = __expf(v0.z - m), e3 = __expf(v0.w - m);
  float e4 = __expf(v1.x - m), e5 = __expf(v1.y - m), e6 = __expf(v1.z - m), e7 = __expf(v1.w - m);
  float s = ((e0 + e1) + (e2 + e3)) + ((e4 + e5) + (e6 + e7));
#pragma unroll
  for (int o = 1; o < 64; o <<= 1) s += __shfl_xor(s, o);
  if ((tid & 63) == 0) red[4 + wid] = s;
  __syncthreads();
  s = (red[4] + red[5]) + (red[6] + red[7]);
  float inv = 1.0f / s;

  ushort4 p0, p1;
  p0.x = f2bf(e0 * inv); p0.y = f2bf(e1 * inv); p0.z = f2bf(e2 * inv); p0.w = f2bf(e3 * inv);
  p1.x = f2bf(e4 * inv); p1.y = f2bf(e5 * inv); p1.z = f2bf(e6 * inv); p1.w = f2bf(e7 * inv);
  ushort4* prow = (ushort4*)(P + t * T_DIM);
  prow[tid * 2] = p0;
  prow[tid * 2 + 1] = p1;
}

// ---------------- launch ----------------
extern "C" void kernel_launch(void* const* d_in, const int* in_sizes, int n_in,
                              void* d_out, int out_size, void* d_ws, size_t ws_size,
                              hipStream_t stream) {
  const float* x = (const float*)d_in[0];     // [8,2048,1024]
  const float* bias = (const float*)d_in[1];  // [2048,2048]
  const float* Wqkv = (const float*)d_in[2];  // [3072,1024]
  const float* bqkv = (const float*)d_in[3];  // [3072]
  const float* Wout = (const float*)d_in[4];  // [1024,1024]
  const float* bout = (const float*)d_in[5];  // [1024]
  float* out = (float*)d_out;                 // [8,2048,1024] fp32

  char* ws = (char*)d_ws;
  unsigned short* Xb    = (unsigned short*)(ws + 0);          // 33.5MB; reused as Valb
  unsigned short* Wqkvb = (unsigned short*)(ws + 33554432);   // 6.3MB
  unsigned short* Woutb = (unsigned short*)(ws + 39845888);   // 2.1MB
  unsigned short* QKVb  = (unsigned short*)(ws + 41943040);   // 100.7MB [b,t,3072]
  unsigned short* VTb   = (unsigned short*)(ws + 142606336);  // 33.5MB  [b,1024,2048]
  unsigned short* biasb = (unsigned short*)(ws + 176160768);  // 8.4MB   [2048,2048] bf16
  float*          S     = (float*)(ws + 184549376);           // 33.5MB  [2,2048,2048] fp32
  unsigned short* P     = (unsigned short*)(ws + 218103808);  // 16.8MB  [2,2048,2048] bf16
  unsigned short* Valb  = Xb;                                 // overlays Xb (dead after QKV)

  const long long sQKV = (long long)T_DIM * 3072;   // per-batch stride in QKVb
  const long long sTT  = (long long)T_DIM * T_DIM;  // per-batch stride in S/P
  const long long sVT  = (long long)E_DIM * T_DIM;
  const long long sTE  = (long long)T_DIM * E_DIM;

  // 1) fp32 -> bf16 conversions
  cvt_bf16<<<16384, 256, 0, stream>>>((const float4*)x, (ushort4*)Xb);
  cvt_bf16<<<3072, 256, 0, stream>>>((const float4*)Wqkv, (ushort4*)Wqkvb);
  cvt_bf16<<<1024, 256, 0, stream>>>((const float4*)Wout, (ushort4*)Woutb);
  cvt_bf16<<<4096, 256, 0, stream>>>((const float4*)bias, (ushort4*)biasb);

  // 2) QKV projection: [16384,3072] = Xb[16384,1024] * Wqkv[3072,1024]^T + bqkv
  gemm_bt<1, unsigned short><<<dim3(128, 24, 1), 256, 0, stream>>>(
      Xb, 1024, 0, Wqkvb, 1024, 0, QKVb, 3072, 0, 1024, bqkv, nullptr, 0, 0.f);

  // 3) V transpose for PV GEMM (B^T layout)
  transpose_v<<<dim3(32, 16, B_DIM), 256, 0, stream>>>(QKVb, VTb);

  // 4) attention in groups of 2 batches (S/P sized for 2)
  for (int g = 0; g < B_DIM / 2; ++g) {
    const unsigned short* Qb = QKVb + (size_t)g * 2 * sQKV;
    // logits: S[z,t,s] = (Q_t . K_s) / 32 + bias[t,s]
    gemm_bt<2, float><<<dim3(16, 16, 2), 256, 0, stream>>>(
        Qb, 3072, sQKV, Qb + 1024, 3072, sQKV, S, T_DIM, sTT, 1024,
        nullptr, biasb, T_DIM, 0.03125f);
    softmax_rows<<<dim3(T_DIM, 2), 256, 0, stream>>>(S, P);
    // values: [2048,1024] = P[2048,2048] * VT[1024,2048]^T
    gemm_bt<0, unsigned short><<<dim3(16, 8, 2), 256, 0, stream>>>(
        P, T_DIM, sTT, VTb + (size_t)g * 2 * sVT, T_DIM, sVT,
        Valb + (size_t)g * 2 * sTE, E_DIM, sTE, T_DIM, nullptr, nullptr, 0, 0.f);
  }

  // 5) output projection: out[16384,1024] = Val[16384,1024] * Wout[1024,1024]^T + bout
  gemm_bt<1, float><<<dim3(128, 8, 1), 256, 0, stream>>>(
      Valb, 1024, 0, Woutb, 1024, 0, out, 1024, 0, 1024, bout, nullptr, 0, 0.f);
}

// Round 3
// 411.433 us; speedup vs baseline: 2.0728x; 1.4363x over previous
//
#include <hip/hip_runtime.h>
#include <hip/hip_bf16.h>

// Problem: B=8, T=2048, D_IN=D_EMB=D_OUT=1024
#define B_DIM 8
#define T_DIM 2048
#define E_DIM 1024

typedef __attribute__((ext_vector_type(8))) short short8;
typedef __attribute__((ext_vector_type(4))) float f32x4;

__device__ __forceinline__ unsigned short f2bf(float f) {
  union { float f; unsigned u; } v; v.f = f;
  unsigned r = v.u + 0x7fffu + ((v.u >> 16) & 1u);
  return (unsigned short)(r >> 16);
}
__device__ __forceinline__ float bf2f(unsigned short u) {
  union { unsigned u; float f; } v; v.u = ((unsigned)u) << 16;
  return v.f;
}

__device__ __forceinline__ void async16(const void* g, void* l) {
  __builtin_amdgcn_global_load_lds(
      (const __attribute__((address_space(1))) unsigned int*)g,
      (__attribute__((address_space(3))) unsigned int*)l, 16, 0, 0);
}

__device__ __forceinline__ void storeC(float* p, float v) { *p = v; }
__device__ __forceinline__ void storeC(unsigned short* p, float v) { *p = f2bf(v); }

// ---------------- fp32 -> bf16 conversion (vectorized) ----------------
__global__ __launch_bounds__(256) void cvt_bf16(const float4* __restrict__ in,
                                                ushort4* __restrict__ out) {
  size_t i = (size_t)blockIdx.x * 256 + threadIdx.x;
  float4 v = in[i];
  ushort4 o;
  o.x = f2bf(v.x); o.y = f2bf(v.y); o.z = f2bf(v.z); o.w = f2bf(v.w);
  out[i] = o;
}

// ============ 256x256 8-phase bf16 GEMM: C[M,N] = A[M,K]*B[N,K]^T (+epilogue) ========
// 512 threads = 8 waves (2M x 4N), per-wave 128x64 output, BK=64, 128KB LDS.
// LDS: A[buf][half][128][64], B likewise at +64KB. Chunk swizzle q' = q ^ (row&7)
// applied on BOTH stage-source and ds_read (rule #21: both-sides-or-neither).
// Schedule per K-tile t (4 phases): phase0 reads B(8)+A fr0,1(4), stages t+1.A0 (->nxt);
// p1 reads A fr2,3, stages t+1.A1; p2 reads A fr4,5, stages t+2.B0 (->cur.B, dead
// since p0 + 2 barriers); p3 reads A fr6,7, stages t+2.B1, then counted vmcnt(4)
// (t+2.B stays in flight across the boundary barrier - T4). Two s_barrier per phase.
// EPI 0: none; 1: +biasv[n]; 2: *scale + bf2f(biasm[m*ldbm+n])
template <int EPI, typename OutT>
__global__ __launch_bounds__(512, 2) void gemm8p(
    const unsigned short* __restrict__ A, int lda, long long strA,
    const unsigned short* __restrict__ Bm, int ldb, long long strB,
    OutT* __restrict__ C, int ldc, long long strC, int K,
    const float* __restrict__ biasv,
    const unsigned short* __restrict__ biasm, int ldbm, float scale) {
  __shared__ __align__(16) char lds[131072];
  const int tid = threadIdx.x;
  const int wid = tid >> 6, lane = tid & 63;
  const int wm = wid >> 2, wn = wid & 3;
  const int l16 = lane & 15, lk = lane >> 4;

  // XCD-aware block swizzle (all launches have gridDim.x*gridDim.y % 8 == 0)
  const int nx = gridDim.x;
  const int nwg = nx * gridDim.y;
  const int bid = blockIdx.y * nx + blockIdx.x;
  const int swz = (bid & 7) * (nwg >> 3) + (bid >> 3);
  const int tm = (swz % nx) * 256, tn = (swz / nx) * 256;

  A += (size_t)blockIdx.z * strA;
  Bm += (size_t)blockIdx.z * strB;
  C += (size_t)blockIdx.z * strC;

  const int nt = K >> 6;  // K-tiles (callers guarantee nt >= 2)

  // per-lane swizzled chunk byte-offsets for ds_read (row&7 == l16&7 everywhere used)
  const int q0 = ((lk ^ (l16 & 7)) << 4);
  const int q1 = (((lk | 4) ^ (l16 & 7)) << 4);
  // staging source decomposition: lane covers LDS chunk (row=srow within 8-row strip,
  // chunk lane&7); source chunk pre-swizzled so LDS is involution-consistent.
  const int srow = lane >> 3;
  const int scol = ((lane & 7) ^ srow) << 3;  // element offset

  f32x4 acc[8][4];
#pragma unroll
  for (int i = 0; i < 8; ++i)
#pragma unroll
    for (int j = 0; j < 4; ++j) acc[i][j] = (f32x4){0.f, 0.f, 0.f, 0.f};

#define STAGE_A(tt, h)                                                              \
  {                                                                                 \
    const int buf_ = (tt) & 1, k0_ = (tt) << 6;                                     \
    { const unsigned short* g_ =                                                    \
          A + (size_t)(tm + (h) * 128 + wid * 16 + srow) * lda + k0_ + scol;        \
      async16(g_, lds + (buf_ * 2 + (h)) * 16384 + wid * 2048); }                   \
    { const unsigned short* g_ =                                                    \
          A + (size_t)(tm + (h) * 128 + wid * 16 + 8 + srow) * lda + k0_ + scol;    \
      async16(g_, lds + (buf_ * 2 + (h)) * 16384 + wid * 2048 + 1024); }            \
  }
#define STAGE_B(tt, h)                                                              \
  {                                                                                 \
    const int buf_ = (tt) & 1, k0_ = (tt) << 6;                                     \
    { const unsigned short* g_ =                                                    \
          Bm + (size_t)(tn + (h) * 128 + wid * 16 + srow) * ldb + k0_ + scol;       \
      async16(g_, lds + 65536 + (buf_ * 2 + (h)) * 16384 + wid * 2048); }           \
    { const unsigned short* g_ =                                                    \
          Bm + (size_t)(tn + (h) * 128 + wid * 16 + 8 + srow) * ldb + k0_ + scol;   \
      async16(g_, lds + 65536 + (buf_ * 2 + (h)) * 16384 + wid * 2048 + 1024); }    \
  }

  // prologue: tile0 all 4 halves + tile1 B halves (B is consumed 2 tiles ahead)
  STAGE_A(0, 0); STAGE_A(0, 1); STAGE_B(0, 0); STAGE_B(0, 1);
  STAGE_B(1, 0); STAGE_B(1, 1);
  asm volatile("s_waitcnt vmcnt(4)" ::: "memory");  // tile0 landed; tile1.B in flight
  __builtin_amdgcn_s_barrier();

  short8 b[4][2];
  for (int t = 0; t < nt; ++t) {
    const int cur = t & 1;
    const char* aB = lds + (cur * 2 + wm) * 16384 + l16 * 128;
    const char* bB = lds + 65536 + (cur * 2 + (wn >> 1)) * 16384 + ((wn & 1) * 64 + l16) * 128;
#pragma unroll
    for (int p = 0; p < 4; ++p) {
      short8 a00 = *(const short8*)(aB + (2 * p) * 2048 + q0);
      short8 a01 = *(const short8*)(aB + (2 * p) * 2048 + q1);
      short8 a10 = *(const short8*)(aB + (2 * p + 1) * 2048 + q0);
      short8 a11 = *(const short8*)(aB + (2 * p + 1) * 2048 + q1);
      if (p == 0) {
#pragma unroll
        for (int wc = 0; wc < 4; ++wc) {
          b[wc][0] = *(const short8*)(bB + wc * 2048 + q0);
          b[wc][1] = *(const short8*)(bB + wc * 2048 + q1);
        }
      }
      if (p == 0 && t + 1 < nt) STAGE_A(t + 1, 0);
      if (p == 1 && t + 1 < nt) STAGE_A(t + 1, 1);
      if (p == 2 && t + 2 < nt) STAGE_B(t + 2, 0);
      if (p == 3 && t + 2 < nt) STAGE_B(t + 2, 1);
      if (p == 3) {
        if (t + 2 < nt) asm volatile("s_waitcnt vmcnt(4)" ::: "memory");
        else            asm volatile("s_waitcnt vmcnt(0)" ::: "memory");
      }
      __builtin_amdgcn_s_barrier();
      __builtin_amdgcn_sched_barrier(0);
      __builtin_amdgcn_s_setprio(1);
#pragma unroll
      for (int wc = 0; wc < 4; ++wc) {
        acc[2 * p][wc] = __builtin_amdgcn_mfma_f32_16x16x32_bf16(a00, b[wc][0], acc[2 * p][wc], 0, 0, 0);
        acc[2 * p][wc] = __builtin_amdgcn_mfma_f32_16x16x32_bf16(a01, b[wc][1], acc[2 * p][wc], 0, 0, 0);
        acc[2 * p + 1][wc] = __builtin_amdgcn_mfma_f32_16x16x32_bf16(a10, b[wc][0], acc[2 * p + 1][wc], 0, 0, 0);
        acc[2 * p + 1][wc] = __builtin_amdgcn_mfma_f32_16x16x32_bf16(a11, b[wc][1], acc[2 * p + 1][wc], 0, 0, 0);
      }
      __builtin_amdgcn_s_setprio(0);
      __builtin_amdgcn_sched_barrier(0);
      __builtin_amdgcn_s_barrier();
    }
  }
#undef STAGE_A
#undef STAGE_B

  // epilogue: D row=(lane>>4)*4+r, col=lane&15 per 16x16 frag (verified mapping)
#pragma unroll
  for (int fr = 0; fr < 8; ++fr)
#pragma unroll
    for (int wc = 0; wc < 4; ++wc) {
      const int col = tn + wn * 64 + wc * 16 + l16;
      const int rbase = tm + wm * 128 + fr * 16 + lk * 4;
#pragma unroll
      for (int r = 0; r < 4; ++r) {
        float v = acc[fr][wc][r];
        const int row = rbase + r;
        if (EPI == 1) v += biasv[col];
        if (EPI == 2) v = v * scale + bf2f(biasm[(size_t)row * ldbm + col]);
        storeC(&C[(size_t)row * ldc + col], v);
      }
    }
}

// ---------------- V transpose: VT[b][d][s] = V[b][s][d] (from QKV buffer) ----------------
__global__ __launch_bounds__(256) void transpose_v(const unsigned short* __restrict__ qkv,
                                                   unsigned short* __restrict__ vt) {
  __shared__ unsigned short tl[64][65];
  const int b = blockIdx.z;
  const int s0 = blockIdx.x * 64, d0 = blockIdx.y * 64;
  const int tx = threadIdx.x & 63, ty = threadIdx.x >> 6;
#pragma unroll
  for (int it = 0; it < 16; ++it) {
    int r = it * 4 + ty;
    tl[r][tx] = qkv[((size_t)b * T_DIM + s0 + r) * 3072 + 2048 + d0 + tx];
  }
  __syncthreads();
#pragma unroll
  for (int it = 0; it < 16; ++it) {
    int r = it * 4 + ty;
    vt[((size_t)b * E_DIM + d0 + r) * T_DIM + s0 + tx] = tl[tx][r];
  }
}

// ---------------- row softmax, in-place: P(bf16) overwrites first half of S row -------
__global__ __launch_bounds__(256) void softmax_rows(float* __restrict__ S) {
  float* row = S + (size_t)blockIdx.y * ((size_t)T_DIM * T_DIM) + (size_t)blockIdx.x * T_DIM;
  const int tid = threadIdx.x;
  const int wid = tid >> 6;
  __shared__ float red[8];

  float4 v0 = ((const float4*)row)[tid * 2];
  float4 v1 = ((const float4*)row)[tid * 2 + 1];
  float m = fmaxf(fmaxf(fmaxf(v0.x, v0.y), fmaxf(v0.z, v0.w)),
                  fmaxf(fmaxf(v1.x, v1.y), fmaxf(v1.z, v1.w)));
#pragma unroll
  for (int o = 1; o < 64; o <<= 1) m = fmaxf(m, __shfl_xor(m, o));
  if ((tid & 63) == 0) red[wid] = m;
  __syncthreads();
  m = fmaxf(fmaxf(red[0], red[1]), fmaxf(red[2], red[3]));

  float e0 = __expf(v0.x - m), e1 = __expf(v0.y - m), e2 = __expf(v0.z - m), e3 = __expf(v0.w - m);
  float e4 = __expf(v1.x - m), e5 = __expf(v1.y - m), e6 = __expf(v1.z - m), e7 = __expf(v1.w - m);
  float s = ((e0 + e1) + (e2 + e3)) + ((e4 + e5) + (e6 + e7));
#pragma unroll
  for (int o = 1; o < 64; o <<= 1) s += __shfl_xor(s, o);
  if ((tid & 63) == 0) red[4 + wid] = s;
  __syncthreads();
  s = (red[4] + red[5]) + (red[6] + red[7]);
  float inv = 1.0f / s;

  // all reads completed before the reduction barriers above -> in-place write is safe
  ushort4 p0, p1;
  p0.x = f2bf(e0 * inv); p0.y = f2bf(e1 * inv); p0.z = f2bf(e2 * inv); p0.w = f2bf(e3 * inv);
  p1.x = f2bf(e4 * inv); p1.y = f2bf(e5 * inv); p1.z = f2bf(e6 * inv); p1.w = f2bf(e7 * inv);
  ushort4* prow = (ushort4*)row;
  prow[tid * 2] = p0;
  prow[tid * 2 + 1] = p1;
}

// ---------------- launch ----------------
extern "C" void kernel_launch(void* const* d_in, const int* in_sizes, int n_in,
                              void* d_out, int out_size, void* d_ws, size_t ws_size,
                              hipStream_t stream) {
  const float* x = (const float*)d_in[0];     // [8,2048,1024]
  const float* bias = (const float*)d_in[1];  // [2048,2048]
  const float* Wqkv = (const float*)d_in[2];  // [3072,1024]
  const float* bqkv = (const float*)d_in[3];  // [3072]
  const float* Wout = (const float*)d_in[4];  // [1024,1024]
  const float* bout = (const float*)d_in[5];  // [1024]
  float* out = (float*)d_out;                 // [8,2048,1024] fp32

  char* ws = (char*)d_ws;
  unsigned short* Xb    = (unsigned short*)(ws + 0);          // 33.5MB; reused as Valb
  unsigned short* Wqkvb = (unsigned short*)(ws + 33554432);   // 6.3MB
  unsigned short* Woutb = (unsigned short*)(ws + 39845888);   // 2.1MB
  unsigned short* QKVb  = (unsigned short*)(ws + 41943040);   // 100.7MB [b,t,3072]
  unsigned short* VTb   = (unsigned short*)(ws + 142606336);  // 33.5MB  [b,1024,2048]
  unsigned short* biasb = (unsigned short*)(ws + 176160768);  // 8.4MB   [2048,2048] bf16
  float*          S     = (float*)(ws + 184549376);           // NG x 16.8MB fp32 (P in-place)
  unsigned short* Valb  = Xb;                                 // overlays Xb (dead after QKV)

  // batches per attention group, limited by workspace for S
  const size_t sbase = 184549376ull, sper = 16777216ull;
  int NG = (ws_size >= sbase + 8 * sper) ? 8 : (ws_size >= sbase + 4 * sper) ? 4 : 2;

  const long long sQKV = (long long)T_DIM * 3072;          // elements
  const long long sTTf = (long long)T_DIM * T_DIM;         // floats (S batch stride)
  const long long sTTs = 2 * sTTf;                         // shorts (P batch stride)
  const long long sVT  = (long long)E_DIM * T_DIM;
  const long long sTE  = (long long)T_DIM * E_DIM;

  // 1) fp32 -> bf16 conversions
  cvt_bf16<<<16384, 256, 0, stream>>>((const float4*)x, (ushort4*)Xb);
  cvt_bf16<<<3072, 256, 0, stream>>>((const float4*)Wqkv, (ushort4*)Wqkvb);
  cvt_bf16<<<1024, 256, 0, stream>>>((const float4*)Wout, (ushort4*)Woutb);
  cvt_bf16<<<4096, 256, 0, stream>>>((const float4*)bias, (ushort4*)biasb);

  // 2) QKV projection: [16384,3072] = Xb[16384,1024]*Wqkv^T + bqkv
  gemm8p<1, unsigned short><<<dim3(64, 12, 1), 512, 0, stream>>>(
      Xb, 1024, 0, Wqkvb, 1024, 0, QKVb, 3072, 0, 1024, bqkv, nullptr, 0, 0.f);

  // 3) V transpose for PV GEMM (B^T layout)
  transpose_v<<<dim3(32, 16, B_DIM), 256, 0, stream>>>(QKVb, VTb);

  // 4) attention in groups of NG batches
  for (int g = 0; g < B_DIM / NG; ++g) {
    const unsigned short* Qb = QKVb + (size_t)g * NG * sQKV;
    gemm8p<2, float><<<dim3(8, 8, NG), 512, 0, stream>>>(
        Qb, 3072, sQKV, Qb + 1024, 3072, sQKV, S, T_DIM, sTTf, 1024,
        nullptr, biasb, T_DIM, 0.03125f);
    softmax_rows<<<dim3(T_DIM, NG), 256, 0, stream>>>(S);
    gemm8p<0, unsigned short><<<dim3(8, 4, NG), 512, 0, stream>>>(
        (const unsigned short*)S, 2 * T_DIM, sTTs,
        VTb + (size_t)g * NG * sVT, T_DIM, sVT,
        Valb + (size_t)g * NG * sTE, E_DIM, sTE, T_DIM, nullptr, nullptr, 0, 0.f);
  }

  // 5) output projection: out = Val[16384,1024]*Wout^T + bout
  gemm8p<1, float><<<dim3(64, 4, 1), 512, 0, stream>>>(
      Valb, 1024, 0, Woutb, 1024, 0, out, 1024, 0, 1024, bout, nullptr, 0, 0.f);
}

// Round 4
// 408.453 us; speedup vs baseline: 2.0879x; 1.0073x over previous
//
#include <hip/hip_runtime.h>
#include <hip/hip_bf16.h>

// Problem: B=8, T=2048, D_IN=D_EMB=D_OUT=1024
#define B_DIM 8
#define T_DIM 2048
#define E_DIM 1024

typedef __attribute__((ext_vector_type(8))) short short8;
typedef __attribute__((ext_vector_type(4))) float f32x4;

__device__ __forceinline__ unsigned short f2bf(float f) {
  union { float f; unsigned u; } v; v.f = f;
  unsigned r = v.u + 0x7fffu + ((v.u >> 16) & 1u);
  return (unsigned short)(r >> 16);
}
__device__ __forceinline__ float bf2f(unsigned short u) {
  union { unsigned u; float f; } v; v.u = ((unsigned)u) << 16;
  return v.f;
}

__device__ __forceinline__ void async16(const void* g, void* l) {
  __builtin_amdgcn_global_load_lds(
      (const __attribute__((address_space(1))) unsigned int*)g,
      (__attribute__((address_space(3))) unsigned int*)l, 16, 0, 0);
}

__device__ __forceinline__ void storeC(float* p, float v) { *p = v; }
__device__ __forceinline__ void storeC(unsigned short* p, float v) { *p = f2bf(v); }

// ---------------- fp32 -> bf16 conversion (vectorized) ----------------
__global__ __launch_bounds__(256) void cvt_bf16(const float4* __restrict__ in,
                                                ushort4* __restrict__ out) {
  size_t i = (size_t)blockIdx.x * 256 + threadIdx.x;
  float4 v = in[i];
  ushort4 o;
  o.x = f2bf(v.x); o.y = f2bf(v.y); o.z = f2bf(v.z); o.w = f2bf(v.w);
  out[i] = o;
}

// ============ 256x256 8-phase bf16 GEMM: C[M,N] = A[M,K]*B[N,K]^T (+epilogue) ========
// 512 threads = 8 waves (2M x 4N), per-wave 128x64 output, BK=64, 128KB LDS.
// Chunk swizzle q' = q ^ (row&7) on BOTH stage-source and ds_read (rule #21).
// Fragment READ-AHEAD: phase p's slot issues ds_reads for phase p+1's A-frags
// (ping-pong aF0/aF1); they stay in flight across the barrier and drain via the
// compiler's counted lgkmcnt just before use (m201's lgkmcnt(8) idiom).
// Staging: A(t+1) at p0/p1 (-> buf nxt), B(t+2) at p2/p3 (-> B-buf cur, dead
// since p0 + barriers). Counted vmcnt(4) at p3 only: retires A(t+1), keeps
// B(t+2) in flight across the tile boundary (T4: never drain in main loop).
// EPI 0: none; 1: +biasv[col]; 2: *scale + bf2f(biasm[row*ldbm+col]); 3: +biasv[row]
template <int EPI, typename OutT>
__global__ __launch_bounds__(512, 2) void gemm8p(
    const unsigned short* __restrict__ A, int lda, long long strA,
    const unsigned short* __restrict__ Bm, int ldb, long long strB,
    OutT* __restrict__ C, int ldc, long long strC, int K,
    const float* __restrict__ biasv,
    const unsigned short* __restrict__ biasm, int ldbm, float scale) {
  __shared__ __align__(16) char lds[131072];
  const int tid = threadIdx.x;
  const int wid = tid >> 6, lane = tid & 63;
  const int wm = wid >> 2, wn = wid & 3;
  const int l16 = lane & 15, lk = lane >> 4;

  // XCD-aware block swizzle (all launches have gridDim.x*gridDim.y % 8 == 0)
  const int nx = gridDim.x;
  const int nwg = nx * gridDim.y;
  const int bid = blockIdx.y * nx + blockIdx.x;
  const int swz = (bid & 7) * (nwg >> 3) + (bid >> 3);
  const int tm = (swz % nx) * 256, tn = (swz / nx) * 256;

  A += (size_t)blockIdx.z * strA;
  Bm += (size_t)blockIdx.z * strB;
  C += (size_t)blockIdx.z * strC;

  const int nt = K >> 6;  // K-tiles (callers guarantee nt >= 2)

  // swizzled chunk byte-offsets for ds_read (row&7 == l16&7 in all uses)
  const int q0 = ((lk ^ (l16 & 7)) << 4);
  const int q1 = (((lk | 4) ^ (l16 & 7)) << 4);
  // staging source decomposition (source chunk pre-swizzled, LDS dest linear)
  const int srow = lane >> 3;
  const int scol = ((lane & 7) ^ srow) << 3;  // element offset

  f32x4 acc[8][4];
#pragma unroll
  for (int i = 0; i < 8; ++i)
#pragma unroll
    for (int j = 0; j < 4; ++j) acc[i][j] = (f32x4){0.f, 0.f, 0.f, 0.f};

  short8 aF0[4], aF1[4], bF[4][2];

#define STAGE_A(tt, h)                                                              \
  {                                                                                 \
    const int buf_ = (tt) & 1, k0_ = (tt) << 6;                                     \
    { const unsigned short* g_ =                                                    \
          A + (size_t)(tm + (h) * 128 + wid * 16 + srow) * lda + k0_ + scol;        \
      async16(g_, lds + (buf_ * 2 + (h)) * 16384 + wid * 2048); }                   \
    { const unsigned short* g_ =                                                    \
          A + (size_t)(tm + (h) * 128 + wid * 16 + 8 + srow) * lda + k0_ + scol;    \
      async16(g_, lds + (buf_ * 2 + (h)) * 16384 + wid * 2048 + 1024); }            \
  }
#define STAGE_B(tt, h)                                                              \
  {                                                                                 \
    const int buf_ = (tt) & 1, k0_ = (tt) << 6;                                     \
    { const unsigned short* g_ =                                                    \
          Bm + (size_t)(tn + (h) * 128 + wid * 16 + srow) * ldb + k0_ + scol;       \
      async16(g_, lds + 65536 + (buf_ * 2 + (h)) * 16384 + wid * 2048); }           \
    { const unsigned short* g_ =                                                    \
          Bm + (size_t)(tn + (h) * 128 + wid * 16 + 8 + srow) * ldb + k0_ + scol;   \
      async16(g_, lds + 65536 + (buf_ * 2 + (h)) * 16384 + wid * 2048 + 1024); }    \
  }
#define READA(dst, fr)                                          \
  {                                                             \
    dst[0] = *(const short8*)(aB + (fr) * 2048 + q0);           \
    dst[1] = *(const short8*)(aB + (fr) * 2048 + q1);           \
    dst[2] = *(const short8*)(aB + ((fr) + 1) * 2048 + q0);     \
    dst[3] = *(const short8*)(aB + ((fr) + 1) * 2048 + q1);     \
  }
#define MFMAP(fr, f)                                                                      \
  {                                                                                       \
    _Pragma("unroll")                                                                     \
    for (int wc = 0; wc < 4; ++wc) {                                                      \
      acc[fr][wc] = __builtin_amdgcn_mfma_f32_16x16x32_bf16(f[0], bF[wc][0], acc[fr][wc], 0, 0, 0); \
      acc[fr][wc] = __builtin_amdgcn_mfma_f32_16x16x32_bf16(f[1], bF[wc][1], acc[fr][wc], 0, 0, 0); \
      acc[(fr) + 1][wc] = __builtin_amdgcn_mfma_f32_16x16x32_bf16(f[2], bF[wc][0], acc[(fr) + 1][wc], 0, 0, 0); \
      acc[(fr) + 1][wc] = __builtin_amdgcn_mfma_f32_16x16x32_bf16(f[3], bF[wc][1], acc[(fr) + 1][wc], 0, 0, 0); \
    }                                                                                     \
  }

  // prologue: tile0 all 4 halves + tile1 B halves (B consumed 2 tiles ahead)
  STAGE_A(0, 0); STAGE_A(0, 1); STAGE_B(0, 0); STAGE_B(0, 1);
  STAGE_B(1, 0); STAGE_B(1, 1);
  asm volatile("s_waitcnt vmcnt(4)" ::: "memory");  // tile0 landed; tile1.B in flight
  __builtin_amdgcn_s_barrier();

  for (int t = 0; t < nt; ++t) {
    const int cur = t & 1;
    const char* aB = lds + (cur * 2 + wm) * 16384 + l16 * 128;
    const char* bB = lds + 65536 + (cur * 2 + (wn >> 1)) * 16384 + ((wn & 1) * 64 + l16) * 128;

    // ---- phase 0: cold reads (rows0,1 + B) + ahead reads (rows2,3) ----
    READA(aF0, 0);
#pragma unroll
    for (int wc = 0; wc < 4; ++wc) {
      bF[wc][0] = *(const short8*)(bB + wc * 2048 + q0);
      bF[wc][1] = *(const short8*)(bB + wc * 2048 + q1);
    }
    READA(aF1, 2);
    if (t + 1 < nt) STAGE_A(t + 1, 0);
    __builtin_amdgcn_s_barrier();
    __builtin_amdgcn_s_setprio(1);
    MFMAP(0, aF0);
    __builtin_amdgcn_s_setprio(0);
    __builtin_amdgcn_s_barrier();

    // ---- phase 1: ahead reads rows4,5 ----
    READA(aF0, 4);
    if (t + 1 < nt) STAGE_A(t + 1, 1);
    __builtin_amdgcn_s_barrier();
    __builtin_amdgcn_s_setprio(1);
    MFMAP(2, aF1);
    __builtin_amdgcn_s_setprio(0);
    __builtin_amdgcn_s_barrier();

    // ---- phase 2: ahead reads rows6,7 ----
    READA(aF1, 6);
    if (t + 2 < nt) STAGE_B(t + 2, 0);
    __builtin_amdgcn_s_barrier();
    __builtin_amdgcn_s_setprio(1);
    MFMAP(4, aF0);
    __builtin_amdgcn_s_setprio(0);
    __builtin_amdgcn_s_barrier();

    // ---- phase 3: no reads; counted vmcnt keeps B(t+2) in flight ----
    if (t + 2 < nt) STAGE_B(t + 2, 1);
    if (t + 2 < nt) asm volatile("s_waitcnt vmcnt(4)" ::: "memory");
    else            asm volatile("s_waitcnt vmcnt(0)" ::: "memory");
    __builtin_amdgcn_s_barrier();
    __builtin_amdgcn_s_setprio(1);
    MFMAP(6, aF1);
    __builtin_amdgcn_s_setprio(0);
    __builtin_amdgcn_s_barrier();
  }
#undef STAGE_A
#undef STAGE_B
#undef READA
#undef MFMAP

  // epilogue: D row=(lane>>4)*4+r, col=lane&15 per 16x16 frag (verified mapping)
#pragma unroll
  for (int fr = 0; fr < 8; ++fr)
#pragma unroll
    for (int wc = 0; wc < 4; ++wc) {
      const int col = tn + wn * 64 + wc * 16 + l16;
      const int rbase = tm + wm * 128 + fr * 16 + lk * 4;
#pragma unroll
      for (int r = 0; r < 4; ++r) {
        float v = acc[fr][wc][r];
        const int row = rbase + r;
        if (EPI == 1) v += biasv[col];
        if (EPI == 2) v = v * scale + bf2f(biasm[(size_t)row * ldbm + col]);
        if (EPI == 3) v += biasv[row];
        storeC(&C[(size_t)row * ldc + col], v);
      }
    }
}

// ---------------- row softmax, in-place: P(bf16) overwrites first half of S row -------
__global__ __launch_bounds__(256) void softmax_rows(float* __restrict__ S) {
  float* row = S + (size_t)blockIdx.y * ((size_t)T_DIM * T_DIM) + (size_t)blockIdx.x * T_DIM;
  const int tid = threadIdx.x;
  const int wid = tid >> 6;
  __shared__ float red[8];

  float4 v0 = ((const float4*)row)[tid * 2];
  float4 v1 = ((const float4*)row)[tid * 2 + 1];
  float m = fmaxf(fmaxf(fmaxf(v0.x, v0.y), fmaxf(v0.z, v0.w)),
                  fmaxf(fmaxf(v1.x, v1.y), fmaxf(v1.z, v1.w)));
#pragma unroll
  for (int o = 1; o < 64; o <<= 1) m = fmaxf(m, __shfl_xor(m, o));
  if ((tid & 63) == 0) red[wid] = m;
  __syncthreads();
  m = fmaxf(fmaxf(red[0], red[1]), fmaxf(red[2], red[3]));

  float e0 = __expf(v0.x - m), e1 = __expf(v0.y - m), e2 = __expf(v0.z - m), e3 = __expf(v0.w - m);
  float e4 = __expf(v1.x - m), e5 = __expf(v1.y - m), e6 = __expf(v1.z - m), e7 = __expf(v1.w - m);
  float s = ((e0 + e1) + (e2 + e3)) + ((e4 + e5) + (e6 + e7));
#pragma unroll
  for (int o = 1; o < 64; o <<= 1) s += __shfl_xor(s, o);
  if ((tid & 63) == 0) red[4 + wid] = s;
  __syncthreads();
  s = (red[4] + red[5]) + (red[6] + red[7]);
  float inv = 1.0f / s;

  ushort4 p0, p1;
  p0.x = f2bf(e0 * inv); p0.y = f2bf(e1 * inv); p0.z = f2bf(e2 * inv); p0.w = f2bf(e3 * inv);
  p1.x = f2bf(e4 * inv); p1.y = f2bf(e5 * inv); p1.z = f2bf(e6 * inv); p1.w = f2bf(e7 * inv);
  ushort4* prow = (ushort4*)row;
  prow[tid * 2] = p0;
  prow[tid * 2 + 1] = p1;
}

// ---------------- launch ----------------
extern "C" void kernel_launch(void* const* d_in, const int* in_sizes, int n_in,
                              void* d_out, int out_size, void* d_ws, size_t ws_size,
                              hipStream_t stream) {
  const float* x = (const float*)d_in[0];     // [8,2048,1024]
  const float* bias = (const float*)d_in[1];  // [2048,2048]
  const float* Wqkv = (const float*)d_in[2];  // [3072,1024]
  const float* bqkv = (const float*)d_in[3];  // [3072]
  const float* Wout = (const float*)d_in[4];  // [1024,1024]
  const float* bout = (const float*)d_in[5];  // [1024]
  float* out = (float*)d_out;                 // [8,2048,1024] fp32

  char* ws = (char*)d_ws;
  unsigned short* Xb    = (unsigned short*)(ws + 0);          // 33.5MB; reused as Valb
  unsigned short* Wqkvb = (unsigned short*)(ws + 33554432);   // 6.3MB [3072,1024]
  unsigned short* Woutb = (unsigned short*)(ws + 39845888);   // 2.1MB
  unsigned short* QKb   = (unsigned short*)(ws + 41943040);   // 67MB [b,t,2048] (Q|K)
  unsigned short* VTb   = (unsigned short*)(ws + 109051904);  // 33.5MB [1024, 8*2048]
  unsigned short* biasb = (unsigned short*)(ws + 142606336);  // 8.4MB [2048,2048] bf16
  float*          S     = (float*)(ws + 150994944);           // NG x 16.8MB fp32 (P in-place)
  unsigned short* Valb  = Xb;                                 // overlays Xb (dead after V-GEMM)

  // batches per attention group, limited by workspace for S
  const size_t sbase = 150994944ull, sper = 16777216ull;
  int NG = (ws_size >= sbase + 8 * sper) ? 8 : (ws_size >= sbase + 4 * sper) ? 4 : 2;

  const long long sQK  = (long long)T_DIM * 2048;          // elements
  const long long sTTf = (long long)T_DIM * T_DIM;         // floats (S batch stride)
  const long long sTTs = 2 * sTTf;                         // shorts (P batch stride)
  const long long sTE  = (long long)T_DIM * E_DIM;

  // 1) fp32 -> bf16 conversions
  cvt_bf16<<<16384, 256, 0, stream>>>((const float4*)x, (ushort4*)Xb);
  cvt_bf16<<<3072, 256, 0, stream>>>((const float4*)Wqkv, (ushort4*)Wqkvb);
  cvt_bf16<<<1024, 256, 0, stream>>>((const float4*)Wout, (ushort4*)Woutb);
  cvt_bf16<<<4096, 256, 0, stream>>>((const float4*)bias, (ushort4*)biasb);

  // 2) QK projection: [16384,2048] = Xb[16384,1024]*Wqk^T + bqk
  gemm8p<1, unsigned short><<<dim3(64, 8, 1), 512, 0, stream>>>(
      Xb, 1024, 0, Wqkvb, 1024, 0, QKb, 2048, 0, 1024, bqkv, nullptr, 0, 0.f);

  // 3) V projection, TRANSPOSED output: VT[d, b*T+t] = Wv[d,:].x[b,t,:] + bv[d]
  gemm8p<3, unsigned short><<<dim3(4, 64, 1), 512, 0, stream>>>(
      Wqkvb + (size_t)2048 * 1024, 1024, 0, Xb, 1024, 0,
      VTb, 16384, 0, 1024, bqkv + 2048, nullptr, 0, 0.f);

  // 4) attention in groups of NG batches
  for (int g = 0; g < B_DIM / NG; ++g) {
    const unsigned short* Qb = QKb + (size_t)g * NG * sQK;
    gemm8p<2, float><<<dim3(8, 8, NG), 512, 0, stream>>>(
        Qb, 2048, sQK, Qb + 1024, 2048, sQK, S, T_DIM, sTTf, 1024,
        nullptr, biasb, T_DIM, 0.03125f);
    softmax_rows<<<dim3(T_DIM, NG), 256, 0, stream>>>(S);
    // values: [2048,1024] = P[2048,2048] * VT_batch[1024,2048]^T
    gemm8p<0, unsigned short><<<dim3(8, 4, NG), 512, 0, stream>>>(
        (const unsigned short*)S, 2 * T_DIM, sTTs,
        VTb + (size_t)g * NG * T_DIM, 8 * T_DIM, T_DIM,
        Valb + (size_t)g * NG * sTE, E_DIM, sTE, T_DIM, nullptr, nullptr, 0, 0.f);
  }

  // 5) output projection: out = Val[16384,1024]*Wout^T + bout
  gemm8p<1, float><<<dim3(64, 4, 1), 512, 0, stream>>>(
      Valb, 1024, 0, Woutb, 1024, 0, out, 1024, 0, 1024, bout, nullptr, 0, 0.f);
}

// Round 5
// 337.655 us; speedup vs baseline: 2.5257x; 1.2097x over previous
//
#include <hip/hip_runtime.h>
#include <hip/hip_bf16.h>

// Problem: B=8, T=2048, D_IN=D_EMB=D_OUT=1024
#define B_DIM 8
#define T_DIM 2048
#define E_DIM 1024

typedef __attribute__((ext_vector_type(8))) short short8;
typedef __attribute__((ext_vector_type(4))) float f32x4;

__device__ __forceinline__ unsigned short f2bf(float f) {
  union { float f; unsigned u; } v; v.f = f;
  unsigned r = v.u + 0x7fffu + ((v.u >> 16) & 1u);
  return (unsigned short)(r >> 16);
}
__device__ __forceinline__ float bf2f(unsigned short u) {
  union { unsigned u; float f; } v; v.u = ((unsigned)u) << 16;
  return v.f;
}

__device__ __forceinline__ void async16(const void* g, void* l) {
  __builtin_amdgcn_global_load_lds(
      (const __attribute__((address_space(1))) unsigned int*)g,
      (__attribute__((address_space(3))) unsigned int*)l, 16, 0, 0);
}

__device__ __forceinline__ void storeC(float* p, float v) { *p = v; }
__device__ __forceinline__ void storeC(unsigned short* p, float v) { *p = f2bf(v); }

// ---------------- fp32 -> bf16 conversion (vectorized) ----------------
__global__ __launch_bounds__(256) void cvt_bf16(const float4* __restrict__ in,
                                                ushort4* __restrict__ out) {
  size_t i = (size_t)blockIdx.x * 256 + threadIdx.x;
  float4 v = in[i];
  ushort4 o;
  o.x = f2bf(v.x); o.y = f2bf(v.y); o.z = f2bf(v.z); o.w = f2bf(v.w);
  out[i] = o;
}

// ============ 256x256 8-phase bf16 GEMM: C[M,N] = A[M,K]*B[N,K]^T (+epilogue) ========
// 512 threads = 8 waves (2M x 4N), per-wave 128x64 output, BK=64, 128KB LDS.
// Chunk swizzle q' = q ^ (row&7) on BOTH stage-source and ds_read (rule #21).
// Counted vmcnt(4) at phase 3 keeps B(t+2) in flight across the tile boundary (T4).
// EPI: 0 none; 1 +biasv[col]; 3 +biasv[row];
//      4 exp(v*scale + biasm[row*ldbm+col])  (unnormalized softmax numerator, bf16 out)
//      5 v * (1 / biasv[z*ldbm + row])       (late softmax rescale; biasv = row sums)
template <int EPI, typename OutT>
__global__ __launch_bounds__(512, 2) void gemm8p(
    const unsigned short* __restrict__ A, int lda, long long strA,
    const unsigned short* __restrict__ Bm, int ldb, long long strB,
    OutT* __restrict__ C, int ldc, long long strC, int K,
    const float* __restrict__ biasv,
    const float* __restrict__ biasm, int ldbm, float scale) {
  __shared__ __align__(16) char lds[131072];
  const int tid = threadIdx.x;
  const int wid = tid >> 6, lane = tid & 63;
  const int wm = wid >> 2, wn = wid & 3;
  const int l16 = lane & 15, lk = lane >> 4;
  const int zz = blockIdx.z;

  // XCD-aware block swizzle (all launches have gridDim.x*gridDim.y % 8 == 0)
  const int nx = gridDim.x;
  const int nwg = nx * gridDim.y;
  const int bid = blockIdx.y * nx + blockIdx.x;
  const int swz = (bid & 7) * (nwg >> 3) + (bid >> 3);
  const int tm = (swz % nx) * 256, tn = (swz / nx) * 256;

  A += (size_t)zz * strA;
  Bm += (size_t)zz * strB;
  C += (size_t)zz * strC;

  const int nt = K >> 6;  // K-tiles (callers guarantee nt >= 2)

  // swizzled chunk byte-offsets for ds_read (row&7 == l16&7 in all uses)
  const int q0 = ((lk ^ (l16 & 7)) << 4);
  const int q1 = (((lk | 4) ^ (l16 & 7)) << 4);
  // staging source decomposition (source chunk pre-swizzled, LDS dest linear)
  const int srow = lane >> 3;
  const int scol = ((lane & 7) ^ srow) << 3;  // element offset

  f32x4 acc[8][4];
#pragma unroll
  for (int i = 0; i < 8; ++i)
#pragma unroll
    for (int j = 0; j < 4; ++j) acc[i][j] = (f32x4){0.f, 0.f, 0.f, 0.f};

  short8 aF0[4], aF1[4], bF[4][2];

#define STAGE_A(tt, h)                                                              \
  {                                                                                 \
    const int buf_ = (tt) & 1, k0_ = (tt) << 6;                                     \
    { const unsigned short* g_ =                                                    \
          A + (size_t)(tm + (h) * 128 + wid * 16 + srow) * lda + k0_ + scol;        \
      async16(g_, lds + (buf_ * 2 + (h)) * 16384 + wid * 2048); }                   \
    { const unsigned short* g_ =                                                    \
          A + (size_t)(tm + (h) * 128 + wid * 16 + 8 + srow) * lda + k0_ + scol;    \
      async16(g_, lds + (buf_ * 2 + (h)) * 16384 + wid * 2048 + 1024); }            \
  }
#define STAGE_B(tt, h)                                                              \
  {                                                                                 \
    const int buf_ = (tt) & 1, k0_ = (tt) << 6;                                     \
    { const unsigned short* g_ =                                                    \
          Bm + (size_t)(tn + (h) * 128 + wid * 16 + srow) * ldb + k0_ + scol;       \
      async16(g_, lds + 65536 + (buf_ * 2 + (h)) * 16384 + wid * 2048); }           \
    { const unsigned short* g_ =                                                    \
          Bm + (size_t)(tn + (h) * 128 + wid * 16 + 8 + srow) * ldb + k0_ + scol;   \
      async16(g_, lds + 65536 + (buf_ * 2 + (h)) * 16384 + wid * 2048 + 1024); }    \
  }
#define READA(dst, fr)                                          \
  {                                                             \
    dst[0] = *(const short8*)(aB + (fr) * 2048 + q0);           \
    dst[1] = *(const short8*)(aB + (fr) * 2048 + q1);           \
    dst[2] = *(const short8*)(aB + ((fr) + 1) * 2048 + q0);     \
    dst[3] = *(const short8*)(aB + ((fr) + 1) * 2048 + q1);     \
  }
#define MFMAP(fr, f)                                                                      \
  {                                                                                       \
    _Pragma("unroll")                                                                     \
    for (int wc = 0; wc < 4; ++wc) {                                                      \
      acc[fr][wc] = __builtin_amdgcn_mfma_f32_16x16x32_bf16(f[0], bF[wc][0], acc[fr][wc], 0, 0, 0); \
      acc[fr][wc] = __builtin_amdgcn_mfma_f32_16x16x32_bf16(f[1], bF[wc][1], acc[fr][wc], 0, 0, 0); \
      acc[(fr) + 1][wc] = __builtin_amdgcn_mfma_f32_16x16x32_bf16(f[2], bF[wc][0], acc[(fr) + 1][wc], 0, 0, 0); \
      acc[(fr) + 1][wc] = __builtin_amdgcn_mfma_f32_16x16x32_bf16(f[3], bF[wc][1], acc[(fr) + 1][wc], 0, 0, 0); \
    }                                                                                     \
  }

  // prologue: tile0 all 4 halves + tile1 B halves (B consumed 2 tiles ahead)
  STAGE_A(0, 0); STAGE_A(0, 1); STAGE_B(0, 0); STAGE_B(0, 1);
  STAGE_B(1, 0); STAGE_B(1, 1);
  asm volatile("s_waitcnt vmcnt(4)" ::: "memory");  // tile0 landed; tile1.B in flight
  __builtin_amdgcn_s_barrier();

  for (int t = 0; t < nt; ++t) {
    const int cur = t & 1;
    const char* aB = lds + (cur * 2 + wm) * 16384 + l16 * 128;
    const char* bB = lds + 65536 + (cur * 2 + (wn >> 1)) * 16384 + ((wn & 1) * 64 + l16) * 128;

    // ---- phase 0: cold reads (rows0,1 + B) + ahead reads (rows2,3) ----
    READA(aF0, 0);
#pragma unroll
    for (int wc = 0; wc < 4; ++wc) {
      bF[wc][0] = *(const short8*)(bB + wc * 2048 + q0);
      bF[wc][1] = *(const short8*)(bB + wc * 2048 + q1);
    }
    READA(aF1, 2);
    if (t + 1 < nt) STAGE_A(t + 1, 0);
    __builtin_amdgcn_s_barrier();
    __builtin_amdgcn_s_setprio(1);
    MFMAP(0, aF0);
    __builtin_amdgcn_s_setprio(0);
    __builtin_amdgcn_s_barrier();

    // ---- phase 1: ahead reads rows4,5 ----
    READA(aF0, 4);
    if (t + 1 < nt) STAGE_A(t + 1, 1);
    __builtin_amdgcn_s_barrier();
    __builtin_amdgcn_s_setprio(1);
    MFMAP(2, aF1);
    __builtin_amdgcn_s_setprio(0);
    __builtin_amdgcn_s_barrier();

    // ---- phase 2: ahead reads rows6,7 ----
    READA(aF1, 6);
    if (t + 2 < nt) STAGE_B(t + 2, 0);
    __builtin_amdgcn_s_barrier();
    __builtin_amdgcn_s_setprio(1);
    MFMAP(4, aF0);
    __builtin_amdgcn_s_setprio(0);
    __builtin_amdgcn_s_barrier();

    // ---- phase 3: no reads; counted vmcnt keeps B(t+2) in flight ----
    if (t + 2 < nt) STAGE_B(t + 2, 1);
    if (t + 2 < nt) asm volatile("s_waitcnt vmcnt(4)" ::: "memory");
    else            asm volatile("s_waitcnt vmcnt(0)" ::: "memory");
    __builtin_amdgcn_s_barrier();
    __builtin_amdgcn_s_setprio(1);
    MFMAP(6, aF1);
    __builtin_amdgcn_s_setprio(0);
    __builtin_amdgcn_s_barrier();
  }
#undef STAGE_A
#undef STAGE_B
#undef READA
#undef MFMAP

  // epilogue: D row=(lane>>4)*4+r, col=lane&15 per 16x16 frag (verified mapping)
#pragma unroll
  for (int fr = 0; fr < 8; ++fr) {
    const int rbase = tm + wm * 128 + fr * 16 + lk * 4;
    float rin[4];
    if (EPI == 5) {
#pragma unroll
      for (int r = 0; r < 4; ++r)
        rin[r] = 1.0f / biasv[(size_t)zz * ldbm + rbase + r];
    }
#pragma unroll
    for (int wc = 0; wc < 4; ++wc) {
      const int col = tn + wn * 64 + wc * 16 + l16;
#pragma unroll
      for (int r = 0; r < 4; ++r) {
        float v = acc[fr][wc][r];
        const int row = rbase + r;
        if (EPI == 1) v += biasv[col];
        if (EPI == 3) v += biasv[row];
        if (EPI == 4) v = __expf(v * scale + biasm[(size_t)row * ldbm + col]);
        if (EPI == 5) v *= rin[r];
        storeC(&C[(size_t)row * ldc + col], v);
      }
    }
  }
}

// ---------------- row sums of expS (bf16): R[row] = sum_s P[row,s] ----------------
__global__ __launch_bounds__(256) void rowsum(const unsigned short* __restrict__ P,
                                              float* __restrict__ R) {
  const size_t row = (size_t)blockIdx.y * T_DIM + blockIdx.x;
  const int tid = threadIdx.x;
  const int wid = tid >> 6;
  __shared__ float red[4];

  short8 v = ((const short8*)(P + row * T_DIM))[tid];
  float s = 0.f;
#pragma unroll
  for (int j = 0; j < 8; ++j) s += bf2f((unsigned short)v[j]);
#pragma unroll
  for (int o = 1; o < 64; o <<= 1) s += __shfl_xor(s, o);
  if ((tid & 63) == 0) red[wid] = s;
  __syncthreads();
  if (tid == 0) R[row] = (red[0] + red[1]) + (red[2] + red[3]);
}

// ---------------- launch ----------------
extern "C" void kernel_launch(void* const* d_in, const int* in_sizes, int n_in,
                              void* d_out, int out_size, void* d_ws, size_t ws_size,
                              hipStream_t stream) {
  const float* x = (const float*)d_in[0];     // [8,2048,1024]
  const float* bias = (const float*)d_in[1];  // [2048,2048] fp32
  const float* Wqkv = (const float*)d_in[2];  // [3072,1024]
  const float* bqkv = (const float*)d_in[3];  // [3072]
  const float* Wout = (const float*)d_in[4];  // [1024,1024]
  const float* bout = (const float*)d_in[5];  // [1024]
  float* out = (float*)d_out;                 // [8,2048,1024] fp32

  char* ws = (char*)d_ws;
  unsigned short* Xb    = (unsigned short*)(ws + 0);          // 33.5MB; reused as Valb
  unsigned short* Wqkvb = (unsigned short*)(ws + 33554432);   // 6.3MB [3072,1024]
  unsigned short* Woutb = (unsigned short*)(ws + 39845888);   // 2.1MB
  unsigned short* QKb   = (unsigned short*)(ws + 41943040);   // 67MB [b,t,2048] (Q|K)
  unsigned short* VTb   = (unsigned short*)(ws + 109051904);  // 33.5MB [1024, 8*2048]
  unsigned short* P     = (unsigned short*)(ws + 142606336);  // 67MB [b,2048,2048] expS bf16
  float*          R     = (float*)(ws + 209715200);           // 64KB [b,2048] row sums
  unsigned short* Valb  = Xb;                                 // overlays Xb (dead after V-GEMM)

  const long long sQK  = (long long)T_DIM * 2048;   // elements
  const long long sTT  = (long long)T_DIM * T_DIM;  // P batch stride (elements)
  const long long sTE  = (long long)T_DIM * E_DIM;

  // 1) fp32 -> bf16 conversions (bias consumed fp32 in-epilogue; no cvt)
  cvt_bf16<<<16384, 256, 0, stream>>>((const float4*)x, (ushort4*)Xb);
  cvt_bf16<<<3072, 256, 0, stream>>>((const float4*)Wqkv, (ushort4*)Wqkvb);
  cvt_bf16<<<1024, 256, 0, stream>>>((const float4*)Wout, (ushort4*)Woutb);

  // 2) QK projection: [16384,2048] = Xb[16384,1024]*Wqk^T + bqk
  gemm8p<1, unsigned short><<<dim3(64, 8, 1), 512, 0, stream>>>(
      Xb, 1024, 0, Wqkvb, 1024, 0, QKb, 2048, 0, 1024, bqkv, nullptr, 0, 0.f);

  // 3) V projection, TRANSPOSED output: VT[d, b*T+t] = Wv[d,:].x[b,t,:] + bv[d]
  gemm8p<3, unsigned short><<<dim3(4, 64, 1), 512, 0, stream>>>(
      Wqkvb + (size_t)2048 * 1024, 1024, 0, Xb, 1024, 0,
      VTb, 16384, 0, 1024, bqkv + 2048, nullptr, 0, 0.f);

  // 4) logits + fused exp (no max-sub; logits bounded ~|2|):
  //    P[z,t,s] = exp((Q_t.K_s)/32 + bias[t,s])  (bf16)
  gemm8p<4, unsigned short><<<dim3(8, 8, B_DIM), 512, 0, stream>>>(
      QKb, 2048, sQK, QKb + 1024, 2048, sQK, P, T_DIM, sTT, 1024,
      nullptr, bias, T_DIM, 0.03125f);

  // 5) deterministic row sums of expS
  rowsum<<<dim3(T_DIM, B_DIM), 256, 0, stream>>>(P, R);

  // 6) PV with late rescale: Val[z,t,d] = (sum_s P[z,t,s]*VT[d,z*T+s]) / R[z,t]
  gemm8p<5, unsigned short><<<dim3(8, 4, B_DIM), 512, 0, stream>>>(
      P, T_DIM, sTT, VTb, 8 * T_DIM, T_DIM,
      Valb, E_DIM, sTE, T_DIM, R, nullptr, T_DIM, 0.f);

  // 7) output projection: out = Val[16384,1024]*Wout^T + bout
  gemm8p<1, float><<<dim3(64, 4, 1), 512, 0, stream>>>(
      Valb, 1024, 0, Woutb, 1024, 0, out, 1024, 0, 1024, bout, nullptr, 0, 0.f);
}